// Round 1
// baseline (2977.486 us; speedup 1.0000x reference)
//
#include <hip/hip_runtime.h>
#include <math.h>

// ---- problem constants (match reference) ----
#define BB 8
#define N_GO 12000
#define N_GENES 20000
#define IN_F 8
#define FF 64
#define D_ATT 5
#define L_DIM 16
#define N_LAST 4000
#define P0_ 4000
#define EPSF 1e-5f

// ============================================================
// row bounds for a sorted (non-decreasing) index array
// rs[r] = first e with src[e]==r, re[r] = last+1; rows absent keep 0/0
__global__ void k_row_bounds(const int* __restrict__ src, int* __restrict__ rs,
                             int* __restrict__ re, int E) {
    int e = blockIdx.x * 256 + threadIdx.x;
    if (e >= E) return;
    int r = src[e];
    if (e == 0 || src[e - 1] != r) rs[r] = e;
    if (e == E - 1 || src[e + 1] != r) re[r] = e + 1;
}

// x0[b,r,f] = sum_{e in row r} data[b, col[e]] * t[f, e]
__global__ void k_gene2go(const float* __restrict__ data, const float* __restrict__ t,
                          const int* __restrict__ col, const int* __restrict__ rs,
                          const int* __restrict__ re, float* __restrict__ x0, int nnz) {
    int idx = blockIdx.x * 256 + threadIdx.x;
    if (idx >= N_GO * IN_F) return;
    int r = idx / IN_F, f = idx % IN_F;
    int b = blockIdx.y;
    float acc = 0.f;
    int e1 = re[r];
    for (int e = rs[r]; e < e1; e++)
        acc += data[b * N_GENES + col[e]] * t[(size_t)f * nnz + e];
    x0[((size_t)b * N_GO + r) * IN_F + f] = acc;
}

// Y[b,n,of] = dot(X[b, n+xoff, :Fin], W[of,:Fin]) ; X batch-stride xbs (floats)
__global__ void k_linear(const float* __restrict__ X, const float* __restrict__ W,
                         float* __restrict__ Y, int n_nodes, int Fin, int Fout,
                         long xbs, int xoff) {
    long idx = (long)blockIdx.x * 256 + threadIdx.x;
    if (idx >= (long)n_nodes * Fout) return;
    int b = blockIdx.y;
    int n = (int)(idx / Fout), of = (int)(idx % Fout);
    const float* xr = X + (size_t)b * xbs + (size_t)(n + xoff) * Fin;
    const float* wr = W + (size_t)of * Fin;
    float acc = 0.f;
    for (int i = 0; i < Fin; i++) acc += xr[i] * wr[i];
    Y[((size_t)b * n_nodes + n) * Fout + of] = acc;
}

// a_src[b,n] = dot(xin, watt[0:64]); a_dst[b,n] = dot(xin, watt[64:128])
__global__ void k_att_ab(const float* __restrict__ Xin, const float* __restrict__ watt,
                         float* __restrict__ a_src, float* __restrict__ a_dst, int n_nodes) {
    int idx = blockIdx.x * 256 + threadIdx.x;
    if (idx >= n_nodes) return;
    int b = blockIdx.y;
    const float* xr = Xin + ((size_t)b * n_nodes + idx) * FF;
    float s0 = 0.f, s1 = 0.f;
    for (int i = 0; i < FF; i++) { float x = xr[i]; s0 += x * watt[i]; s1 += x * watt[FF + i]; }
    a_src[b * n_nodes + idx] = s0;
    a_dst[b * n_nodes + idx] = s1;
}

// vs[b,n] = sigmoid(dot(Xs[b,n,:], w))
__global__ void k_vs(const float* __restrict__ Xs, const float* __restrict__ w,
                     float* __restrict__ vs, int n_nodes) {
    int idx = blockIdx.x * 256 + threadIdx.x;
    if (idx >= n_nodes) return;
    int b = blockIdx.y;
    const float* xr = Xs + ((size_t)b * n_nodes + idx) * FF;
    float s = 0.f;
    for (int i = 0; i < FF; i++) s += xr[i] * w[i];
    vs[b * n_nodes + idx] = 1.f / (1.f + expf(-s));
}

// v[b,e] = exp(tanh(a_src[b,src[e]] + a_dst[b,dst[e]]))
__global__ void k_edge_v(const float* __restrict__ a_src, const float* __restrict__ a_dst,
                         const int* __restrict__ src, const int* __restrict__ dst,
                         float* __restrict__ v, int E, int n_nodes) {
    int e = blockIdx.x * 256 + threadIdx.x;
    if (e >= E) return;
    int b = blockIdx.y;
    v[(size_t)b * E + e] = expf(tanhf(a_src[b * n_nodes + src[e]] + a_dst[b * n_nodes + dst[e]]));
}

// segv[b,r] = sum of v over row run
__global__ void k_segv(const float* __restrict__ v, const int* __restrict__ rs,
                       const int* __restrict__ re, float* __restrict__ segv,
                       int n_nodes, int E) {
    int r = blockIdx.x * 256 + threadIdx.x;
    if (r >= n_nodes) return;
    int b = blockIdx.y;
    float s = 0.f;
    int e1 = re[r];
    for (int e = rs[r]; e < e1; e++) s += v[(size_t)b * E + e];
    segv[b * n_nodes + r] = s;
}

// Xinc[b,r,f] = (1/segv[b,r]) * sum_{e in row r} v[b,e] * Xin[b,dst[e],f]
__global__ void k_agg_rows_enc(const float* __restrict__ Xin, const float* __restrict__ v,
                               const float* __restrict__ segv, const int* __restrict__ dst,
                               const int* __restrict__ rs, const int* __restrict__ re,
                               float* __restrict__ Xinc, int n_nodes, int E) {
    long idx = (long)blockIdx.x * 256 + threadIdx.x;
    if (idx >= (long)n_nodes * FF) return;
    int r = (int)(idx / FF), f = (int)(idx % FF);
    int b = blockIdx.y;
    float sv = segv[b * n_nodes + r];
    float inv = (sv != 0.f) ? 1.f / sv : 0.f;
    float acc = 0.f;
    int e1 = re[r];
    for (int e = rs[r]; e < e1; e++)
        acc += v[(size_t)b * E + e] * Xin[((size_t)b * n_nodes + dst[e]) * FF + f];
    Xinc[((size_t)b * n_nodes + r) * FF + f] = acc * inv;
}

// C += Xs * vs[b,n]   (F=64)
__global__ void k_combine(float* __restrict__ C, const float* __restrict__ Xs,
                          const float* __restrict__ vs, int n_nodes) {
    long idx = (long)blockIdx.x * 256 + threadIdx.x;
    if (idx >= (long)n_nodes * FF) return;
    int b = blockIdx.y;
    int n = (int)(idx / FF);
    size_t o = (size_t)b * n_nodes * FF + idx;
    C[o] += Xs[o] * vs[b * n_nodes + n];
}

// LN over node axis: accumulate sum & sumsq per (b,f)
__global__ void k_ln_stats(const float* __restrict__ X, float* __restrict__ sums,
                           int n_nodes, int Fdim, int npb) {
    int b = blockIdx.y;
    int f = threadIdx.x & (Fdim - 1);
    int nl = threadIdx.x / Fdim;
    int stride = 256 / Fdim;
    int n0 = blockIdx.x * npb;
    int n1 = n0 + npb; if (n1 > n_nodes) n1 = n_nodes;
    const float* xb = X + (size_t)b * n_nodes * Fdim;
    float s1 = 0.f, s2 = 0.f;
    for (int n = n0 + nl; n < n1; n += stride) {
        float x = xb[(size_t)n * Fdim + f];
        s1 += x; s2 += x * x;
    }
    __shared__ float sh1[256], sh2[256];
    sh1[threadIdx.x] = s1; sh2[threadIdx.x] = s2;
    __syncthreads();
    for (int o = 128; o >= Fdim; o >>= 1) {
        if (threadIdx.x < o) { sh1[threadIdx.x] += sh1[threadIdx.x + o]; sh2[threadIdx.x] += sh2[threadIdx.x + o]; }
        __syncthreads();
    }
    if (threadIdx.x < Fdim) {
        atomicAdd(&sums[(b * Fdim + threadIdx.x) * 2],     sh1[threadIdx.x]);
        atomicAdd(&sums[(b * Fdim + threadIdx.x) * 2 + 1], sh2[threadIdx.x]);
    }
}

// Y = relu((X - mu)*rsqrt(var+eps)*g[n] + bb[n]) ; mu,var from sums
__global__ void k_ln_apply_relu(const float* __restrict__ X, const float* __restrict__ sums,
                                const float* __restrict__ g, const float* __restrict__ bb,
                                float* __restrict__ Y, int n_nodes, int Fdim) {
    long idx = (long)blockIdx.x * 256 + threadIdx.x;
    if (idx >= (long)n_nodes * Fdim) return;
    int b = blockIdx.y;
    int n = (int)(idx / Fdim), f = (int)(idx % Fdim);
    float s1 = sums[(b * Fdim + f) * 2], s2 = sums[(b * Fdim + f) * 2 + 1];
    float mu = s1 / n_nodes;
    float var = s2 / n_nodes - mu * mu;
    float rs = rsqrtf(var + EPSF);
    size_t o = (size_t)b * n_nodes * Fdim + idx;
    float y = (X[o] - mu) * rs * g[n] + bb[n];
    Y[o] = fmaxf(y, 0.f);
}

// deg[src[e]] += 1
__global__ void k_deg(const int* __restrict__ src, float* __restrict__ deg, int E) {
    int e = blockIdx.x * 256 + threadIdx.x;
    if (e < E) atomicAdd(&deg[src[e]], 1.0f);
}

// Xg[b,src,f] += (1/deg[src]) * Xout[b,dst,f]   (atomic; dec src unsorted)
__global__ void k_dec_agg(const float* __restrict__ Xout, const float* __restrict__ deg,
                          const int* __restrict__ src, const int* __restrict__ dst,
                          float* __restrict__ Xg, int E, int n_rows, int n_in, int Fdim) {
    long idx = (long)blockIdx.x * 256 + threadIdx.x;
    if (idx >= (long)E * Fdim) return;
    int e = (int)(idx / Fdim), f = (int)(idx % Fdim);
    int b = blockIdx.y;
    float coef = 1.0f / deg[src[e]];
    atomicAdd(&Xg[((size_t)b * n_rows + src[e]) * Fdim + f],
              coef * Xout[((size_t)b * n_in + dst[e]) * Fdim + f]);
}

// Out[b, offset+n, f] += Xs[b, n, f]
__global__ void k_add_region(float* __restrict__ Out, const float* __restrict__ Xs,
                             int n_rows, int offset, int n_in, int Fdim) {
    long idx = (long)blockIdx.x * 256 + threadIdx.x;
    if (idx >= (long)n_in * Fdim) return;
    int b = blockIdx.y;
    Out[((size_t)b * n_rows + offset) * Fdim + idx] += Xs[(size_t)b * n_in * Fdim + idx];
}

// BN over batch axis (B=8) per column, then relu
__global__ void k_bn2d_relu(const float* __restrict__ Y, const float* __restrict__ g,
                            const float* __restrict__ bb, float* __restrict__ Z, int n) {
    int i = blockIdx.x * 256 + threadIdx.x;
    if (i >= n) return;
    float s1 = 0.f, s2 = 0.f;
    for (int b = 0; b < BB; b++) { float y = Y[(size_t)b * n + i]; s1 += y; s2 += y * y; }
    float mu = s1 / BB, var = s2 / BB - mu * mu;
    float rs = rsqrtf(var + EPSF);
    float gg = g[i], bbb = bb[i];
    for (int b = 0; b < BB; b++) {
        float y = Y[(size_t)b * n + i];
        Z[(size_t)b * n + i] = fmaxf((y - mu) * rs * gg + bbb, 0.f);
    }
}

// BN over (batch, d) per node for (B, n, D_ATT), then relu
__global__ void k_bn3d_relu(const float* __restrict__ Y, const float* __restrict__ g,
                            const float* __restrict__ bb, float* __restrict__ Z, int n) {
    int i = blockIdx.x * 256 + threadIdx.x;
    if (i >= n) return;
    float s1 = 0.f, s2 = 0.f;
    for (int b = 0; b < BB; b++)
        for (int d = 0; d < D_ATT; d++) {
            float y = Y[((size_t)b * n + i) * D_ATT + d];
            s1 += y; s2 += y * y;
        }
    float cnt = (float)(BB * D_ATT);
    float mu = s1 / cnt, var = s2 / cnt - mu * mu;
    float rs = rsqrtf(var + EPSF);
    float gg = g[i], bbb = bb[i];
    for (int b = 0; b < BB; b++)
        for (int d = 0; d < D_ATT; d++) {
            size_t o = ((size_t)b * n + i) * D_ATT + d;
            Z[o] = fmaxf((Y[o] - mu) * rs * gg + bbb, 0.f);
        }
}

// xD[b, col[e]] += outD[b, row[e]] * tD[e]
__global__ void k_xd(const float* __restrict__ outD, const float* __restrict__ tD,
                     const int* __restrict__ row, const int* __restrict__ col,
                     float* __restrict__ xD, int nnz) {
    int e = blockIdx.x * 256 + threadIdx.x;
    if (e >= nnz) return;
    int b = blockIdx.y;
    atomicAdd(&xD[(size_t)b * N_GENES + col[e]], outD[(size_t)b * N_GO + row[e]] * tD[e]);
}

// small dense: Y[b,j] = dot(X[b,:K], W[j,:K])
__global__ void k_dense(const float* __restrict__ X, const float* __restrict__ W,
                        float* __restrict__ Y, int K, int Nout) {
    int idx = blockIdx.x * 256 + threadIdx.x;
    if (idx >= BB * Nout) return;
    int b = idx / Nout, j = idx % Nout;
    float acc = 0.f;
    for (int k = 0; k < K; k++) acc += X[(size_t)b * K + k] * W[(size_t)j * K + k];
    Y[(size_t)b * Nout + j] = acc;
}

// ============================================================
extern "C" void kernel_launch(void* const* d_in, const int* in_sizes, int n_in,
                              void* d_out, int out_size, void* d_ws, size_t ws_size,
                              hipStream_t stream) {
    const float* data      = (const float*)d_in[0];
    const float* t         = (const float*)d_in[1];
    const float* t_D       = (const float*)d_in[2];
    const float* w_inc0    = (const float*)d_in[3];
    const float* w_inc1    = (const float*)d_in[4];
    const float* w_s0      = (const float*)d_in[5];
    const float* w_s1      = (const float*)d_in[6];
    const float* w_att_in0 = (const float*)d_in[7];
    const float* w_att_in1 = (const float*)d_in[8];
    const float* w_att_s0  = (const float*)d_in[9];
    const float* w_att_s1  = (const float*)d_in[10];
    const float* gb_g0     = (const float*)d_in[11];
    const float* gb_b0     = (const float*)d_in[12];
    const float* gb_g1     = (const float*)d_in[13];
    const float* gb_b1     = (const float*)d_in[14];
    const float* w_out0    = (const float*)d_in[15];
    const float* w_out1    = (const float*)d_in[16];
    const float* w_sout0   = (const float*)d_in[17];
    const float* w_sout1   = (const float*)d_in[18];
    const float* gbd_g0    = (const float*)d_in[19];
    const float* gbd_b0    = (const float*)d_in[20];
    const float* gbd_g1    = (const float*)d_in[21];
    const float* gbd_b1    = (const float*)d_in[22];
    const float* catt_w    = (const float*)d_in[23];
    const float* catt_bn_g = (const float*)d_in[24];
    const float* catt_bn_b = (const float*)d_in[25];
    const float* conc_w    = (const float*)d_in[26];
    const float* b_bn_g    = (const float*)d_in[27];
    const float* b_bn_b    = (const float*)d_in[28];
    const float* concd_w   = (const float*)d_in[29];
    const float* bd_bn_g   = (const float*)d_in[30];
    const float* bd_bn_b   = (const float*)d_in[31];
    const float* lat_w1    = (const float*)d_in[32];
    const float* lat_bn1_g = (const float*)d_in[33];
    const float* lat_bn1_b = (const float*)d_in[34];
    const float* lat_w2    = (const float*)d_in[35];
    const float* lat_bn2_g = (const float*)d_in[36];
    const float* lat_bn2_b = (const float*)d_in[37];
    const int* Ag_row   = (const int*)d_in[38];
    const int* Ag_col   = (const int*)d_in[39];
    const int* enc_src0 = (const int*)d_in[40];
    const int* enc_dst0 = (const int*)d_in[41];
    const int* enc_src1 = (const int*)d_in[42];
    const int* enc_dst1 = (const int*)d_in[43];
    const int* dec_src0 = (const int*)d_in[44];
    const int* dec_dst0 = (const int*)d_in[45];
    const int* dec_src1 = (const int*)d_in[46];
    const int* dec_dst1 = (const int*)d_in[47];

    const int nnz = in_sizes[2];
    const int E0  = in_sizes[40];
    const int E1  = in_sizes[42];
    const int ED0 = in_sizes[44];
    const int ED1 = in_sizes[46];

    // ---- workspace arena (~105 MB) ----
    char* wsb = (char*)d_ws;
    size_t off = 0;
    auto alloc = [&](size_t bytes) -> void* {
        void* p = wsb + off;
        off += (bytes + 255) & ~(size_t)255;
        return p;
    };
    const size_t ARENA = (size_t)BB * N_GO * FF; // 6.144M floats
    float* P0 = (float*)alloc(ARENA * 4);
    float* P1 = (float*)alloc(ARENA * 4);
    float* P2 = (float*)alloc(ARENA * 4);
    float* P3 = (float*)alloc(ARENA * 4);
    float* EDGEV = (float*)alloc((size_t)BB * E0 * 4);
    float* ASRC = (float*)alloc((size_t)BB * N_GO * 4);
    float* ADST = (float*)alloc((size_t)BB * N_GO * 4);
    float* SEGV = (float*)alloc((size_t)BB * N_GO * 4); // also reused as DEG
    float* VS   = (float*)alloc((size_t)BB * N_GO * 4);
    float* SUMS = (float*)alloc(2 * BB * FF * 4);
    float* ATT  = (float*)alloc((size_t)BB * N_LAST * D_ATT * 4);
    float* CONC = (float*)alloc((size_t)BB * N_GO * 4);
    float* INP  = (float*)alloc((size_t)BB * N_LAST * 4);
    float* OUTD = (float*)alloc((size_t)BB * N_GO * 4);
    float* H1   = (float*)alloc(BB * 32 * 4);
    float* H1R  = (float*)alloc(BB * 32 * 4);
    float* H2   = (float*)alloc(BB * 16 * 4);
    int* RS = (int*)alloc(N_GO * 4);
    int* RE = (int*)alloc(N_GO * 4);
    float* DEG = SEGV;

    float* out_lat = (float*)d_out;                 // (B,16)
    float* out_xd  = out_lat + BB * L_DIM;          // (B,20000)
    float* out_att = out_xd + (size_t)BB * N_GENES; // (B,4000,5)

    dim3 blk(256);
    auto g1 = [](long n) { return dim3((unsigned)((n + 255) / 256)); };
    auto g2 = [](long n, int y) { return dim3((unsigned)((n + 255) / 256), (unsigned)y); };

    // ---- stage 0: gene -> GO ----
    hipMemsetAsync(RS, 0, N_GO * 4, stream);
    hipMemsetAsync(RE, 0, N_GO * 4, stream);
    k_row_bounds<<<g1(nnz), blk, 0, stream>>>(Ag_row, RS, RE, nnz);
    k_gene2go<<<g2((long)N_GO * IN_F, BB), blk, 0, stream>>>(data, t, Ag_col, RS, RE, P0, nnz);

    // ---- encoder 0 (n=12000) ----
    k_linear<<<g2((long)N_GO * FF, BB), blk, 0, stream>>>(P0, w_inc0, P1, N_GO, IN_F, FF, (long)N_GO * IN_F, 0);
    k_linear<<<g2((long)N_GO * FF, BB), blk, 0, stream>>>(P0, w_s0,   P2, N_GO, IN_F, FF, (long)N_GO * IN_F, 0);
    k_att_ab<<<g2(N_GO, BB), blk, 0, stream>>>(P1, w_att_in0, ASRC, ADST, N_GO);
    k_vs<<<g2(N_GO, BB), blk, 0, stream>>>(P2, w_att_s0, VS, N_GO);
    hipMemsetAsync(RS, 0, N_GO * 4, stream);
    hipMemsetAsync(RE, 0, N_GO * 4, stream);
    k_row_bounds<<<g1(E0), blk, 0, stream>>>(enc_src0, RS, RE, E0);
    k_edge_v<<<g2(E0, BB), blk, 0, stream>>>(ASRC, ADST, enc_src0, enc_dst0, EDGEV, E0, N_GO);
    k_segv<<<g2(N_GO, BB), blk, 0, stream>>>(EDGEV, RS, RE, SEGV, N_GO, E0);
    k_agg_rows_enc<<<g2((long)N_GO * FF, BB), blk, 0, stream>>>(P1, EDGEV, SEGV, enc_dst0, RS, RE, P3, N_GO, E0);
    k_combine<<<g2((long)N_GO * FF, BB), blk, 0, stream>>>(P3, P2, VS, N_GO);
    hipMemsetAsync(SUMS, 0, 2 * BB * FF * 4, stream);
    k_ln_stats<<<dim3((N_GO + 511) / 512, BB), blk, 0, stream>>>(P3, SUMS, N_GO, FF, 512);
    k_ln_apply_relu<<<g2((long)N_GO * FF, BB), blk, 0, stream>>>(P3, SUMS, gb_g0, gb_b0, P0, N_GO, FF);

    // ---- encoder 1 (n=8000, x = P0[:,4000:,:] bs=12000*64) ----
    const int N1 = N_GO - P0_; // 8000
    k_linear<<<g2((long)N1 * FF, BB), blk, 0, stream>>>(P0, w_inc1, P1, N1, FF, FF, (long)N_GO * FF, P0_);
    k_linear<<<g2((long)N1 * FF, BB), blk, 0, stream>>>(P0, w_s1,   P2, N1, FF, FF, (long)N_GO * FF, P0_);
    k_att_ab<<<g2(N1, BB), blk, 0, stream>>>(P1, w_att_in1, ASRC, ADST, N1);
    k_vs<<<g2(N1, BB), blk, 0, stream>>>(P2, w_att_s1, VS, N1);
    hipMemsetAsync(RS, 0, N_GO * 4, stream);
    hipMemsetAsync(RE, 0, N_GO * 4, stream);
    k_row_bounds<<<g1(E1), blk, 0, stream>>>(enc_src1, RS, RE, E1);
    k_edge_v<<<g2(E1, BB), blk, 0, stream>>>(ASRC, ADST, enc_src1, enc_dst1, EDGEV, E1, N1);
    k_segv<<<g2(N1, BB), blk, 0, stream>>>(EDGEV, RS, RE, SEGV, N1, E1);
    k_agg_rows_enc<<<g2((long)N1 * FF, BB), blk, 0, stream>>>(P1, EDGEV, SEGV, enc_dst1, RS, RE, P3, N1, E1);
    k_combine<<<g2((long)N1 * FF, BB), blk, 0, stream>>>(P3, P2, VS, N1);
    hipMemsetAsync(SUMS, 0, 2 * BB * FF * 4, stream);
    k_ln_stats<<<dim3((N1 + 511) / 512, BB), blk, 0, stream>>>(P3, SUMS, N1, FF, 512);
    k_ln_apply_relu<<<g2((long)N1 * FF, BB), blk, 0, stream>>>(P3, SUMS, gb_g1, gb_b1, P0, N1, FF);

    // x = P0[:,4000:,:] of (B,8000,64): n=4000, bs=8000*64, xoff=4000
    // ---- heads ----
    k_linear<<<g2((long)N_LAST * D_ATT, BB), blk, 0, stream>>>(P0, catt_w, ATT, N_LAST, FF, D_ATT, (long)N1 * FF, P0_);
    k_bn3d_relu<<<g1(N_LAST), blk, 0, stream>>>(ATT, catt_bn_g, catt_bn_b, out_att, N_LAST);
    k_linear<<<g2(N_LAST, BB), blk, 0, stream>>>(P0, conc_w, CONC, N_LAST, FF, 1, (long)N1 * FF, P0_);
    k_bn2d_relu<<<g1(N_LAST), blk, 0, stream>>>(CONC, b_bn_g, b_bn_b, INP, N_LAST);

    // ---- decoder 0 (in n=4000 -> rows 8000) ----
    k_linear<<<g2((long)N_LAST * FF, BB), blk, 0, stream>>>(P0, w_out0,  P1, N_LAST, FF, FF, (long)N1 * FF, P0_);
    k_linear<<<g2((long)N_LAST * FF, BB), blk, 0, stream>>>(P0, w_sout0, P2, N_LAST, FF, FF, (long)N1 * FF, P0_);
    hipMemsetAsync(DEG, 0, 8000 * 4, stream);
    k_deg<<<g1(ED0), blk, 0, stream>>>(dec_src0, DEG, ED0);
    hipMemsetAsync(P3, 0, (size_t)BB * 8000 * FF * 4, stream);
    k_dec_agg<<<g2((long)ED0 * FF, BB), blk, 0, stream>>>(P1, DEG, dec_src0, dec_dst0, P3, ED0, 8000, N_LAST, FF);
    k_add_region<<<g2((long)N_LAST * FF, BB), blk, 0, stream>>>(P3, P2, 8000, 4000, N_LAST, FF);
    hipMemsetAsync(SUMS, 0, 2 * BB * FF * 4, stream);
    k_ln_stats<<<dim3((8000 + 511) / 512, BB), blk, 0, stream>>>(P3, SUMS, 8000, FF, 512);
    k_ln_apply_relu<<<g2((long)8000 * FF, BB), blk, 0, stream>>>(P3, SUMS, gbd_g0, gbd_b0, P0, 8000, FF);

    // ---- decoder 1 (in n=8000 F=64 -> rows 12000 F=8) ----
    k_linear<<<g2((long)8000 * IN_F, BB), blk, 0, stream>>>(P0, w_out1,  P1, 8000, FF, IN_F, (long)8000 * FF, 0);
    k_linear<<<g2((long)8000 * IN_F, BB), blk, 0, stream>>>(P0, w_sout1, P2, 8000, FF, IN_F, (long)8000 * FF, 0);
    hipMemsetAsync(DEG, 0, N_GO * 4, stream);
    k_deg<<<g1(ED1), blk, 0, stream>>>(dec_src1, DEG, ED1);
    hipMemsetAsync(P3, 0, (size_t)BB * N_GO * IN_F * 4, stream);
    k_dec_agg<<<g2((long)ED1 * IN_F, BB), blk, 0, stream>>>(P1, DEG, dec_src1, dec_dst1, P3, ED1, N_GO, 8000, IN_F);
    k_add_region<<<g2((long)8000 * IN_F, BB), blk, 0, stream>>>(P3, P2, N_GO, 4000, 8000, IN_F);
    hipMemsetAsync(SUMS, 0, 2 * BB * IN_F * 4, stream);
    k_ln_stats<<<dim3((N_GO + 511) / 512, BB), blk, 0, stream>>>(P3, SUMS, N_GO, IN_F, 512);
    k_ln_apply_relu<<<g2((long)N_GO * IN_F, BB), blk, 0, stream>>>(P3, SUMS, gbd_g1, gbd_b1, P0, N_GO, IN_F);

    // ---- out_D, x_D ----
    k_linear<<<g2(N_GO, BB), blk, 0, stream>>>(P0, concd_w, CONC, N_GO, IN_F, 1, (long)N_GO * IN_F, 0);
    k_bn2d_relu<<<g1(N_GO), blk, 0, stream>>>(CONC, bd_bn_g, bd_bn_b, OUTD, N_GO);
    hipMemsetAsync(out_xd, 0, (size_t)BB * N_GENES * 4, stream);
    k_xd<<<g2(nnz, BB), blk, 0, stream>>>(OUTD, t_D, Ag_row, Ag_col, out_xd, nnz);

    // ---- latent MLP ----
    k_dense<<<g1(BB * 32), blk, 0, stream>>>(INP, lat_w1, H1, N_LAST, 32);
    k_bn2d_relu<<<g1(32), blk, 0, stream>>>(H1, lat_bn1_g, lat_bn1_b, H1R, 32);
    k_dense<<<g1(BB * 16), blk, 0, stream>>>(H1R, lat_w2, H2, 32, 16);
    k_bn2d_relu<<<g1(16), blk, 0, stream>>>(H2, lat_bn2_g, lat_bn2_b, out_lat, 16);

    (void)n_in; (void)out_size; (void)ws_size;
}

// Round 2
// 1243.595 us; speedup vs baseline: 2.3943x; 2.3943x over previous
//
#include <hip/hip_runtime.h>
#include <math.h>

// ---- problem constants (match reference) ----
#define BB 8
#define N_GO 12000
#define N_GENES 20000
#define IN_F 8
#define FF 64
#define D_ATT 5
#define L_DIM 16
#define N_LAST 4000
#define P0_ 4000
#define EPSF 1e-5f

// ============================================================
// row bounds for a sorted (non-decreasing) index array
__global__ void k_row_bounds(const int* __restrict__ src, int* __restrict__ rs,
                             int* __restrict__ re, int E) {
    int e = blockIdx.x * 256 + threadIdx.x;
    if (e >= E) return;
    int r = src[e];
    if (e == 0 || src[e - 1] != r) rs[r] = e;
    if (e == E - 1 || src[e + 1] != r) re[r] = e + 1;
}

// x0[b,r,f] = sum_{e in row r} data[b, col[e]] * t[f, e]
__global__ void k_gene2go(const float* __restrict__ data, const float* __restrict__ t,
                          const int* __restrict__ col, const int* __restrict__ rs,
                          const int* __restrict__ re, float* __restrict__ x0, int nnz) {
    int idx = blockIdx.x * 256 + threadIdx.x;
    if (idx >= N_GO * IN_F) return;
    int r = idx / IN_F, f = idx % IN_F;
    int b = blockIdx.y;
    float acc = 0.f;
    int e1 = re[r];
    for (int e = rs[r]; e < e1; e++)
        acc += data[b * N_GENES + col[e]] * t[(size_t)f * nnz + e];
    x0[((size_t)b * N_GO + r) * IN_F + f] = acc;
}

// Y1[b,n,of] = dot(Xrow, W1[of]);  Y2[b,n,of] = dot(Xrow, W2[of])
template<int FIN>
__global__ void k_linear2(const float* __restrict__ X, const float* __restrict__ W1,
                          const float* __restrict__ W2, float* __restrict__ Y1,
                          float* __restrict__ Y2, int n_nodes, int Fout,
                          long xbs, int xoff) {
    long idx = (long)blockIdx.x * 256 + threadIdx.x;
    if (idx >= (long)n_nodes * Fout) return;
    int b = blockIdx.y;
    int n = (int)(idx / Fout), of = (int)(idx % Fout);
    const float4* xr = (const float4*)(X + (size_t)b * xbs + (size_t)(n + xoff) * FIN);
    const float4* w1 = (const float4*)(W1 + (size_t)of * FIN);
    const float4* w2 = (const float4*)(W2 + (size_t)of * FIN);
    float a1 = 0.f, a2 = 0.f;
#pragma unroll
    for (int q = 0; q < FIN / 4; q++) {
        float4 x = xr[q], u = w1[q], v = w2[q];
        a1 += x.x * u.x + x.y * u.y + x.z * u.z + x.w * u.w;
        a2 += x.x * v.x + x.y * v.y + x.z * v.z + x.w * v.w;
    }
    Y1[((size_t)b * n_nodes + n) * Fout + of] = a1;
    Y2[((size_t)b * n_nodes + n) * Fout + of] = a2;
}

// per node: a_src, a_dst from P1; vs = sigmoid(P2 . ws)
__global__ void k_node_scalars(const float* __restrict__ P1, const float* __restrict__ P2,
                               const float* __restrict__ watt, const float* __restrict__ ws,
                               float* __restrict__ ASRC, float* __restrict__ ADST,
                               float* __restrict__ VS, int n_nodes) {
    int i = blockIdx.x * 256 + threadIdx.x;
    if (i >= n_nodes) return;
    int b = blockIdx.y;
    const float4* x1 = (const float4*)(P1 + ((size_t)b * n_nodes + i) * FF);
    const float4* x2 = (const float4*)(P2 + ((size_t)b * n_nodes + i) * FF);
    const float4* wa = (const float4*)watt;
    const float4* wb = (const float4*)(watt + FF);
    const float4* wc = (const float4*)ws;
    float s0 = 0.f, s1 = 0.f, s2 = 0.f;
#pragma unroll
    for (int q = 0; q < FF / 4; q++) {
        float4 a = x1[q], c = x2[q], u = wa[q], v = wb[q], w4 = wc[q];
        s0 += a.x * u.x + a.y * u.y + a.z * u.z + a.w * u.w;
        s1 += a.x * v.x + a.y * v.y + a.z * v.z + a.w * v.w;
        s2 += c.x * w4.x + c.y * w4.y + c.z * w4.z + c.w * w4.w;
    }
    ASRC[b * n_nodes + i] = s0;
    ADST[b * n_nodes + i] = s1;
    VS[b * n_nodes + i] = 1.f / (1.f + expf(-s2));
}

// v[b,e] = exp(tanh(a_src[b,src[e]] + a_dst[b,dst[e]]))
__global__ void k_edge_v(const float* __restrict__ a_src, const float* __restrict__ a_dst,
                         const int* __restrict__ src, const int* __restrict__ dst,
                         float* __restrict__ v, int E, int n_nodes) {
    int e = blockIdx.x * 256 + threadIdx.x;
    if (e >= E) return;
    int b = blockIdx.y;
    v[(size_t)b * E + e] = expf(tanhf(a_src[b * n_nodes + src[e]] + a_dst[b * n_nodes + dst[e]]));
}

// fused: segment-sum of v, weighted gather-agg, + Xs*vs combine  -> Out (pre-LN)
__global__ void k_agg_enc(const float* __restrict__ Xin, const float* __restrict__ v,
                          const float* __restrict__ Xs, const float* __restrict__ vs,
                          const int* __restrict__ dst, const int* __restrict__ rs,
                          const int* __restrict__ re, float* __restrict__ Out,
                          int n_nodes, int E) {
    long idx = (long)blockIdx.x * 256 + threadIdx.x;
    if (idx >= (long)n_nodes * FF) return;
    int r = (int)(idx >> 6), f = (int)(idx & 63);
    int b = blockIdx.y;
    int e0 = rs[r], e1 = re[r];
    float sv = 0.f, acc = 0.f;
    for (int e = e0; e < e1; e++) {
        float vv = v[(size_t)b * E + e];
        sv += vv;
        acc += vv * Xin[((size_t)b * n_nodes + dst[e]) * FF + f];
    }
    float o = (e1 > e0) ? acc / sv : 0.f;
    o += Xs[((size_t)b * n_nodes + r) * FF + f] * vs[b * n_nodes + r];
    Out[((size_t)b * n_nodes + r) * FF + f] = o;
}

// LN over node axis: accumulate sum & sumsq per (b,f)
__global__ void k_ln_stats(const float* __restrict__ X, float* __restrict__ sums,
                           int n_nodes, int Fdim, int npb) {
    int b = blockIdx.y;
    int f = threadIdx.x & (Fdim - 1);
    int nl = threadIdx.x / Fdim;
    int stride = 256 / Fdim;
    int n0 = blockIdx.x * npb;
    int n1 = n0 + npb; if (n1 > n_nodes) n1 = n_nodes;
    const float* xb = X + (size_t)b * n_nodes * Fdim;
    float s1 = 0.f, s2 = 0.f;
    for (int n = n0 + nl; n < n1; n += stride) {
        float x = xb[(size_t)n * Fdim + f];
        s1 += x; s2 += x * x;
    }
    __shared__ float sh1[256], sh2[256];
    sh1[threadIdx.x] = s1; sh2[threadIdx.x] = s2;
    __syncthreads();
    for (int o = 128; o >= Fdim; o >>= 1) {
        if (threadIdx.x < o) { sh1[threadIdx.x] += sh1[threadIdx.x + o]; sh2[threadIdx.x] += sh2[threadIdx.x + o]; }
        __syncthreads();
    }
    if (threadIdx.x < Fdim) {
        atomicAdd(&sums[(b * Fdim + threadIdx.x) * 2],     sh1[threadIdx.x]);
        atomicAdd(&sums[(b * Fdim + threadIdx.x) * 2 + 1], sh2[threadIdx.x]);
    }
}

// Y = relu((X - mu)*rsqrt(var+eps)*g[n] + bb[n])
__global__ void k_ln_apply_relu(const float* __restrict__ X, const float* __restrict__ sums,
                                const float* __restrict__ g, const float* __restrict__ bb,
                                float* __restrict__ Y, int n_nodes, int Fdim) {
    long idx = (long)blockIdx.x * 256 + threadIdx.x;
    if (idx >= (long)n_nodes * Fdim) return;
    int b = blockIdx.y;
    int n = (int)(idx / Fdim);
    int f = (int)(idx % Fdim);
    float s1 = sums[(b * Fdim + f) * 2], s2 = sums[(b * Fdim + f) * 2 + 1];
    float mu = s1 / n_nodes;
    float var = s2 / n_nodes - mu * mu;
    float rs = rsqrtf(var + EPSF);
    size_t o = (size_t)b * n_nodes * Fdim + idx;
    float y = (X[o] - mu) * rs * g[n] + bb[n];
    Y[o] = fmaxf(y, 0.f);
}

// deg[src[e]] += 1
__global__ void k_deg(const int* __restrict__ src, float* __restrict__ deg, int E) {
    int e = blockIdx.x * 256 + threadIdx.x;
    if (e < E) atomicAdd(&deg[src[e]], 1.0f);
}

// Xg[b,src,f] += (1/deg[src]) * Xout[b,dst,f]   (atomic scatter)
__global__ void k_dec_agg(const float* __restrict__ Xout, const float* __restrict__ deg,
                          const int* __restrict__ src, const int* __restrict__ dst,
                          float* __restrict__ Xg, int E, int n_rows, int n_in, int Fdim) {
    long idx = (long)blockIdx.x * 256 + threadIdx.x;
    if (idx >= (long)E * Fdim) return;
    int e = (int)(idx / Fdim), f = (int)(idx % Fdim);
    int b = blockIdx.y;
    float coef = 1.0f / deg[src[e]];
    atomicAdd(&Xg[((size_t)b * n_rows + src[e]) * Fdim + f],
              coef * Xout[((size_t)b * n_in + dst[e]) * Fdim + f]);
}

// Out[b, offset+n, f] += Xs[b, n, f]
__global__ void k_add_region(float* __restrict__ Out, const float* __restrict__ Xs,
                             int n_rows, int offset, int n_in, int Fdim) {
    long idx = (long)blockIdx.x * 256 + threadIdx.x;
    if (idx >= (long)n_in * Fdim) return;
    int b = blockIdx.y;
    Out[((size_t)b * n_rows + offset) * Fdim + idx] += Xs[(size_t)b * n_in * Fdim + idx];
}

// fused head: y[b,d] = X[b,i,:]@W[d,:], BN over (b,d), relu -> Z (B,N_LAST,D_ATT)
__global__ void k_head_att(const float* __restrict__ X, const float* __restrict__ W,
                           const float* __restrict__ g, const float* __restrict__ bb,
                           float* __restrict__ Z, long xbs, int xoff) {
    int i = blockIdx.x * 256 + threadIdx.x;
    if (i >= N_LAST) return;
    float y[BB][D_ATT];
    float s1 = 0.f, s2 = 0.f;
    for (int b = 0; b < BB; b++) {
        const float4* xr = (const float4*)(X + (size_t)b * xbs + (size_t)(i + xoff) * FF);
        float4 xv[16];
#pragma unroll
        for (int q = 0; q < 16; q++) xv[q] = xr[q];
        for (int d = 0; d < D_ATT; d++) {
            const float4* wr = (const float4*)(W + (size_t)d * FF);
            float acc = 0.f;
#pragma unroll
            for (int q = 0; q < 16; q++) {
                float4 u = wr[q];
                acc += xv[q].x * u.x + xv[q].y * u.y + xv[q].z * u.z + xv[q].w * u.w;
            }
            y[b][d] = acc; s1 += acc; s2 += acc * acc;
        }
    }
    const float cnt = (float)(BB * D_ATT);
    float mu = s1 / cnt, var = s2 / cnt - mu * mu;
    float rs = rsqrtf(var + EPSF);
    float gg = g[i], bv = bb[i];
    for (int b = 0; b < BB; b++)
        for (int d = 0; d < D_ATT; d++)
            Z[((size_t)b * N_LAST + i) * D_ATT + d] = fmaxf((y[b][d] - mu) * rs * gg + bv, 0.f);
}

// fused head: y[b] = X[b,i,:]@w, BN over batch, relu -> Z (B, n_nodes)
template<int FIN>
__global__ void k_head_scalar(const float* __restrict__ X, const float* __restrict__ w,
                              const float* __restrict__ g, const float* __restrict__ bb,
                              float* __restrict__ Z, int n_nodes, long xbs, int xoff) {
    int i = blockIdx.x * 256 + threadIdx.x;
    if (i >= n_nodes) return;
    float y[BB];
    float s1 = 0.f, s2 = 0.f;
    const float4* wr = (const float4*)w;
    for (int b = 0; b < BB; b++) {
        const float4* xr = (const float4*)(X + (size_t)b * xbs + (size_t)(i + xoff) * FIN);
        float acc = 0.f;
#pragma unroll
        for (int q = 0; q < FIN / 4; q++) {
            float4 x = xr[q], u = wr[q];
            acc += x.x * u.x + x.y * u.y + x.z * u.z + x.w * u.w;
        }
        y[b] = acc; s1 += acc; s2 += acc * acc;
    }
    float mu = s1 / BB, var = s2 / BB - mu * mu;
    float rs = rsqrtf(var + EPSF);
    float gg = g[i], bv = bb[i];
    for (int b = 0; b < BB; b++)
        Z[(size_t)b * n_nodes + i] = fmaxf((y[b] - mu) * rs * gg + bv, 0.f);
}

// xD[b, col[e]] += outD[b, row[e]] * tD[e]
__global__ void k_xd(const float* __restrict__ outD, const float* __restrict__ tD,
                     const int* __restrict__ row, const int* __restrict__ col,
                     float* __restrict__ xD, int nnz) {
    int e = blockIdx.x * 256 + threadIdx.x;
    if (e >= nnz) return;
    int b = blockIdx.y;
    atomicAdd(&xD[(size_t)b * N_GENES + col[e]], outD[(size_t)b * N_GO + row[e]] * tD[e]);
}

// latent layer 1 fused: H1R[b,j] = relu(bn_j over b of dot(INP[b,:4000], W[j,:4000]))
// grid: 32 blocks (j), 512 threads = 8 waves (wave w == batch b)
__global__ void k_lat1(const float* __restrict__ INP, const float* __restrict__ W,
                       const float* __restrict__ g, const float* __restrict__ bb,
                       float* __restrict__ H1R) {
    int j = blockIdx.x;
    int w = threadIdx.x >> 6;
    int lane = threadIdx.x & 63;
    const float* xr = INP + (size_t)w * N_LAST;
    const float* wr = W + (size_t)j * N_LAST;
    float s = 0.f;
    for (int k = lane; k < N_LAST; k += 64) s += xr[k] * wr[k];
    for (int o = 32; o > 0; o >>= 1) s += __shfl_down(s, o);
    __shared__ float sh[BB];
    if (lane == 0) sh[w] = s;
    __syncthreads();
    if (threadIdx.x < BB) {
        float s1 = 0.f, s2 = 0.f;
        for (int q = 0; q < BB; q++) { float y = sh[q]; s1 += y; s2 += y * y; }
        float mu = s1 / BB, var = s2 / BB - mu * mu;
        float rs = rsqrtf(var + EPSF);
        H1R[threadIdx.x * 32 + j] = fmaxf((sh[threadIdx.x] - mu) * rs * g[j] + bb[j], 0.f);
    }
}

// latent layer 2 fused: out_lat[b,j] = relu(bn_j over b of dot(H1R[b,:32], W2[j,:32]))
// single block, 128 threads (b = tid>>4, j = tid&15)
__global__ void k_lat2(const float* __restrict__ H1R, const float* __restrict__ W2,
                       const float* __restrict__ g, const float* __restrict__ bb,
                       float* __restrict__ out_lat) {
    int b = threadIdx.x >> 4, j = threadIdx.x & 15;
    float acc = 0.f;
    for (int k = 0; k < 32; k++) acc += H1R[b * 32 + k] * W2[j * 32 + k];
    __shared__ float sh[128];
    sh[threadIdx.x] = acc;
    __syncthreads();
    float s1 = 0.f, s2 = 0.f;
    for (int q = 0; q < BB; q++) { float y = sh[q * 16 + j]; s1 += y; s2 += y * y; }
    float mu = s1 / BB, var = s2 / BB - mu * mu;
    float rs = rsqrtf(var + EPSF);
    out_lat[b * 16 + j] = fmaxf((acc - mu) * rs * g[j] + bb[j], 0.f);
}

// ============================================================
extern "C" void kernel_launch(void* const* d_in, const int* in_sizes, int n_in,
                              void* d_out, int out_size, void* d_ws, size_t ws_size,
                              hipStream_t stream) {
    const float* data      = (const float*)d_in[0];
    const float* t         = (const float*)d_in[1];
    const float* t_D       = (const float*)d_in[2];
    const float* w_inc0    = (const float*)d_in[3];
    const float* w_inc1    = (const float*)d_in[4];
    const float* w_s0      = (const float*)d_in[5];
    const float* w_s1      = (const float*)d_in[6];
    const float* w_att_in0 = (const float*)d_in[7];
    const float* w_att_in1 = (const float*)d_in[8];
    const float* w_att_s0  = (const float*)d_in[9];
    const float* w_att_s1  = (const float*)d_in[10];
    const float* gb_g0     = (const float*)d_in[11];
    const float* gb_b0     = (const float*)d_in[12];
    const float* gb_g1     = (const float*)d_in[13];
    const float* gb_b1     = (const float*)d_in[14];
    const float* w_out0    = (const float*)d_in[15];
    const float* w_out1    = (const float*)d_in[16];
    const float* w_sout0   = (const float*)d_in[17];
    const float* w_sout1   = (const float*)d_in[18];
    const float* gbd_g0    = (const float*)d_in[19];
    const float* gbd_b0    = (const float*)d_in[20];
    const float* gbd_g1    = (const float*)d_in[21];
    const float* gbd_b1    = (const float*)d_in[22];
    const float* catt_w    = (const float*)d_in[23];
    const float* catt_bn_g = (const float*)d_in[24];
    const float* catt_bn_b = (const float*)d_in[25];
    const float* conc_w    = (const float*)d_in[26];
    const float* b_bn_g    = (const float*)d_in[27];
    const float* b_bn_b    = (const float*)d_in[28];
    const float* concd_w   = (const float*)d_in[29];
    const float* bd_bn_g   = (const float*)d_in[30];
    const float* bd_bn_b   = (const float*)d_in[31];
    const float* lat_w1    = (const float*)d_in[32];
    const float* lat_bn1_g = (const float*)d_in[33];
    const float* lat_bn1_b = (const float*)d_in[34];
    const float* lat_w2    = (const float*)d_in[35];
    const float* lat_bn2_g = (const float*)d_in[36];
    const float* lat_bn2_b = (const float*)d_in[37];
    const int* Ag_row   = (const int*)d_in[38];
    const int* Ag_col   = (const int*)d_in[39];
    const int* enc_src0 = (const int*)d_in[40];
    const int* enc_dst0 = (const int*)d_in[41];
    const int* enc_src1 = (const int*)d_in[42];
    const int* enc_dst1 = (const int*)d_in[43];
    const int* dec_src0 = (const int*)d_in[44];
    const int* dec_dst0 = (const int*)d_in[45];
    const int* dec_src1 = (const int*)d_in[46];
    const int* dec_dst1 = (const int*)d_in[47];

    const int nnz = in_sizes[2];
    const int E0  = in_sizes[40];
    const int E1  = in_sizes[42];
    const int ED0 = in_sizes[44];
    const int ED1 = in_sizes[46];

    // ---- workspace arena ----
    char* wsb = (char*)d_ws;
    size_t off = 0;
    auto alloc = [&](size_t bytes) -> void* {
        void* p = wsb + off;
        off += (bytes + 255) & ~(size_t)255;
        return p;
    };
    const size_t ARENA = (size_t)BB * N_GO * FF;
    float* P0 = (float*)alloc(ARENA * 4);
    float* P1 = (float*)alloc(ARENA * 4);
    float* P2 = (float*)alloc(ARENA * 4);
    float* P3 = (float*)alloc(ARENA * 4);
    float* EDGEV = (float*)alloc((size_t)BB * E0 * 4);
    float* ASRC = (float*)alloc((size_t)BB * N_GO * 4);
    float* ADST = (float*)alloc((size_t)BB * N_GO * 4);
    float* DEG  = (float*)alloc((size_t)N_GO * 4);
    float* VS   = (float*)alloc((size_t)BB * N_GO * 4);
    float* SUMS = (float*)alloc(2 * BB * FF * 4);
    float* INP  = (float*)alloc((size_t)BB * N_LAST * 4);
    float* OUTD = (float*)alloc((size_t)BB * N_GO * 4);
    float* H1R  = (float*)alloc(BB * 32 * 4);
    int* RS = (int*)alloc(N_GO * 4);
    int* RE = (int*)alloc(N_GO * 4);

    float* out_lat = (float*)d_out;                 // (B,16)
    float* out_xd  = out_lat + BB * L_DIM;          // (B,20000)
    float* out_att = out_xd + (size_t)BB * N_GENES; // (B,4000,5)

    dim3 blk(256);
    auto g1 = [](long n) { return dim3((unsigned)((n + 255) / 256)); };
    auto g2 = [](long n, int y) { return dim3((unsigned)((n + 255) / 256), (unsigned)y); };

    // ---- stage 0: gene -> GO ----
    hipMemsetAsync(RS, 0, N_GO * 4, stream);
    hipMemsetAsync(RE, 0, N_GO * 4, stream);
    k_row_bounds<<<g1(nnz), blk, 0, stream>>>(Ag_row, RS, RE, nnz);
    k_gene2go<<<g2((long)N_GO * IN_F, BB), blk, 0, stream>>>(data, t, Ag_col, RS, RE, P0, nnz);

    // ---- encoder 0 (n=12000) ----
    k_linear2<IN_F><<<g2((long)N_GO * FF, BB), blk, 0, stream>>>(P0, w_inc0, w_s0, P1, P2, N_GO, FF, (long)N_GO * IN_F, 0);
    k_node_scalars<<<g2(N_GO, BB), blk, 0, stream>>>(P1, P2, w_att_in0, w_att_s0, ASRC, ADST, VS, N_GO);
    hipMemsetAsync(RS, 0, N_GO * 4, stream);
    hipMemsetAsync(RE, 0, N_GO * 4, stream);
    k_row_bounds<<<g1(E0), blk, 0, stream>>>(enc_src0, RS, RE, E0);
    k_edge_v<<<g2(E0, BB), blk, 0, stream>>>(ASRC, ADST, enc_src0, enc_dst0, EDGEV, E0, N_GO);
    k_agg_enc<<<g2((long)N_GO * FF, BB), blk, 0, stream>>>(P1, EDGEV, P2, VS, enc_dst0, RS, RE, P3, N_GO, E0);
    hipMemsetAsync(SUMS, 0, 2 * BB * FF * 4, stream);
    k_ln_stats<<<dim3((N_GO + 511) / 512, BB), blk, 0, stream>>>(P3, SUMS, N_GO, FF, 512);
    k_ln_apply_relu<<<g2((long)N_GO * FF, BB), blk, 0, stream>>>(P3, SUMS, gb_g0, gb_b0, P0, N_GO, FF);

    // ---- encoder 1 (n=8000, x = P0[:,4000:,:]) ----
    const int N1 = N_GO - P0_; // 8000
    k_linear2<FF><<<g2((long)N1 * FF, BB), blk, 0, stream>>>(P0, w_inc1, w_s1, P1, P2, N1, FF, (long)N_GO * FF, P0_);
    k_node_scalars<<<g2(N1, BB), blk, 0, stream>>>(P1, P2, w_att_in1, w_att_s1, ASRC, ADST, VS, N1);
    hipMemsetAsync(RS, 0, N_GO * 4, stream);
    hipMemsetAsync(RE, 0, N_GO * 4, stream);
    k_row_bounds<<<g1(E1), blk, 0, stream>>>(enc_src1, RS, RE, E1);
    k_edge_v<<<g2(E1, BB), blk, 0, stream>>>(ASRC, ADST, enc_src1, enc_dst1, EDGEV, E1, N1);
    k_agg_enc<<<g2((long)N1 * FF, BB), blk, 0, stream>>>(P1, EDGEV, P2, VS, enc_dst1, RS, RE, P3, N1, E1);
    hipMemsetAsync(SUMS, 0, 2 * BB * FF * 4, stream);
    k_ln_stats<<<dim3((N1 + 511) / 512, BB), blk, 0, stream>>>(P3, SUMS, N1, FF, 512);
    k_ln_apply_relu<<<g2((long)N1 * FF, BB), blk, 0, stream>>>(P3, SUMS, gb_g1, gb_b1, P0, N1, FF);

    // ---- heads (x = P0[:,4000:,:] of (B,8000,64)) ----
    k_head_att<<<g1(N_LAST), blk, 0, stream>>>(P0, catt_w, catt_bn_g, catt_bn_b, out_att, (long)N1 * FF, P0_);
    k_head_scalar<FF><<<g1(N_LAST), blk, 0, stream>>>(P0, conc_w, b_bn_g, b_bn_b, INP, N_LAST, (long)N1 * FF, P0_);

    // ---- decoder 0 (in n=4000 -> rows 8000) ----
    k_linear2<FF><<<g2((long)N_LAST * FF, BB), blk, 0, stream>>>(P0, w_out0, w_sout0, P1, P2, N_LAST, FF, (long)N1 * FF, P0_);
    hipMemsetAsync(DEG, 0, 8000 * 4, stream);
    k_deg<<<g1(ED0), blk, 0, stream>>>(dec_src0, DEG, ED0);
    hipMemsetAsync(P3, 0, (size_t)BB * 8000 * FF * 4, stream);
    k_dec_agg<<<g2((long)ED0 * FF, BB), blk, 0, stream>>>(P1, DEG, dec_src0, dec_dst0, P3, ED0, 8000, N_LAST, FF);
    k_add_region<<<g2((long)N_LAST * FF, BB), blk, 0, stream>>>(P3, P2, 8000, 4000, N_LAST, FF);
    hipMemsetAsync(SUMS, 0, 2 * BB * FF * 4, stream);
    k_ln_stats<<<dim3((8000 + 511) / 512, BB), blk, 0, stream>>>(P3, SUMS, 8000, FF, 512);
    k_ln_apply_relu<<<g2((long)8000 * FF, BB), blk, 0, stream>>>(P3, SUMS, gbd_g0, gbd_b0, P0, 8000, FF);

    // ---- decoder 1 (in n=8000 F=64 -> rows 12000 F=8) ----
    k_linear2<FF><<<g2((long)8000 * IN_F, BB), blk, 0, stream>>>(P0, w_out1, w_sout1, P1, P2, 8000, IN_F, (long)8000 * FF, 0);
    hipMemsetAsync(DEG, 0, N_GO * 4, stream);
    k_deg<<<g1(ED1), blk, 0, stream>>>(dec_src1, DEG, ED1);
    hipMemsetAsync(P3, 0, (size_t)BB * N_GO * IN_F * 4, stream);
    k_dec_agg<<<g2((long)ED1 * IN_F, BB), blk, 0, stream>>>(P1, DEG, dec_src1, dec_dst1, P3, ED1, N_GO, 8000, IN_F);
    k_add_region<<<g2((long)8000 * IN_F, BB), blk, 0, stream>>>(P3, P2, N_GO, 4000, 8000, IN_F);
    hipMemsetAsync(SUMS, 0, 2 * BB * IN_F * 4, stream);
    k_ln_stats<<<dim3((N_GO + 511) / 512, BB), blk, 0, stream>>>(P3, SUMS, N_GO, IN_F, 512);
    k_ln_apply_relu<<<g2((long)N_GO * IN_F, BB), blk, 0, stream>>>(P3, SUMS, gbd_g1, gbd_b1, P0, N_GO, IN_F);

    // ---- out_D head + x_D scatter ----
    k_head_scalar<IN_F><<<g1(N_GO), blk, 0, stream>>>(P0, concd_w, bd_bn_g, bd_bn_b, OUTD, N_GO, (long)N_GO * IN_F, 0);
    hipMemsetAsync(out_xd, 0, (size_t)BB * N_GENES * 4, stream);
    k_xd<<<g2(nnz, BB), blk, 0, stream>>>(OUTD, t_D, Ag_row, Ag_col, out_xd, nnz);

    // ---- latent MLP (fused) ----
    k_lat1<<<dim3(32), dim3(512), 0, stream>>>(INP, lat_w1, lat_bn1_g, lat_bn1_b, H1R);
    k_lat2<<<dim3(1), dim3(128), 0, stream>>>(H1R, lat_w2, lat_bn2_g, lat_bn2_b, out_lat);

    (void)n_in; (void)out_size; (void)ws_size;
}

// Round 3
// 886.811 us; speedup vs baseline: 3.3575x; 1.4023x over previous
//
#include <hip/hip_runtime.h>
#include <math.h>

// ---- problem constants (match reference) ----
#define BB 8
#define N_GO 12000
#define N_GENES 20000
#define IN_F 8
#define FF 64
#define D_ATT 5
#define L_DIM 16
#define N_LAST 4000
#define P0_ 4000
#define EPSF 1e-5f

// ============================================================
// row bounds for a sorted (non-decreasing) index array
__global__ void k_row_bounds(const int* __restrict__ src, int* __restrict__ rs,
                             int* __restrict__ re, int E) {
    int e = blockIdx.x * 256 + threadIdx.x;
    if (e >= E) return;
    int r = src[e];
    if (e == 0 || src[e - 1] != r) rs[r] = e;
    if (e == E - 1 || src[e + 1] != r) re[r] = e + 1;
}

// wave per GO row: lanes = 8 edge-slots x 8 features; all batches inside
__global__ void k_gene2go_w(const float* __restrict__ data, const float* __restrict__ t,
                            const int* __restrict__ col, const int* __restrict__ rs,
                            const int* __restrict__ re, float* __restrict__ x0, int nnz) {
    int wid = blockIdx.x * 4 + (threadIdx.x >> 6);
    if (wid >= N_GO) return;
    int lane = threadIdx.x & 63;
    int f = lane & 7, eo = lane >> 3;
    int e0 = rs[wid], e1 = re[wid];
    float acc[BB];
#pragma unroll
    for (int b = 0; b < BB; b++) acc[b] = 0.f;
    for (int e = e0; e < e1; e += 8) {
        int ee = e + eo;
        bool ok = ee < e1;
        int ec = ok ? ee : (e1 - 1);
        int c = col[ec];
        float tv = ok ? t[(size_t)f * nnz + ee] : 0.f;
#pragma unroll
        for (int b = 0; b < BB; b++)
            acc[b] += tv * data[b * N_GENES + c];
    }
#pragma unroll
    for (int b = 0; b < BB; b++) {
        acc[b] += __shfl_xor(acc[b], 8);
        acc[b] += __shfl_xor(acc[b], 16);
        acc[b] += __shfl_xor(acc[b], 32);
    }
    if (lane < IN_F) {
#pragma unroll
        for (int b = 0; b < BB; b++)
            x0[((size_t)b * N_GO + wid) * IN_F + lane] = acc[b];
    }
}

// dual linear with weights held in registers. lane owns output-feature `of`;
// X row loads are wave-uniform broadcasts; stores coalesced.
template<int FIN, int FOUT>
__global__ void k_linear2_reg(const float* __restrict__ X, const float* __restrict__ W1,
                              const float* __restrict__ W2, float* __restrict__ Y1,
                              float* __restrict__ Y2, int n_nodes, long xbs, int xoff,
                              int total_waves) {
    constexpr int NPW = 64 / FOUT;  // node slots per wave
    int wid = blockIdx.x * 4 + (threadIdx.x >> 6);
    int lane = threadIdx.x & 63;
    int of = lane % FOUT;
    int slot = lane / FOUT;
    float4 w1q[FIN / 4], w2q[FIN / 4];
    const float4* w1p = (const float4*)(W1 + (size_t)of * FIN);
    const float4* w2p = (const float4*)(W2 + (size_t)of * FIN);
#pragma unroll
    for (int q = 0; q < FIN / 4; q++) { w1q[q] = w1p[q]; w2q[q] = w2p[q]; }
    for (long n0 = (long)wid * NPW; n0 < n_nodes; n0 += (long)total_waves * NPW) {
        int n = (int)n0 + slot;
        bool ok = (n < n_nodes);
        int nn = ok ? n : (n_nodes - 1);
        for (int b = 0; b < BB; b++) {
            const float4* xr = (const float4*)(X + (size_t)b * xbs + (size_t)(nn + xoff) * FIN);
            float a1 = 0.f, a2 = 0.f;
#pragma unroll
            for (int q = 0; q < FIN / 4; q++) {
                float4 x = xr[q];
                a1 += x.x * w1q[q].x + x.y * w1q[q].y + x.z * w1q[q].z + x.w * w1q[q].w;
                a2 += x.x * w2q[q].x + x.y * w2q[q].y + x.z * w2q[q].z + x.w * w2q[q].w;
            }
            if (ok) {
                Y1[((size_t)b * n_nodes + n) * FOUT + of] = a1;
                Y2[((size_t)b * n_nodes + n) * FOUT + of] = a2;
            }
        }
    }
}

// per node: a_src, a_dst from P1; vs = sigmoid(P2 . ws)
__global__ void k_node_scalars(const float* __restrict__ P1, const float* __restrict__ P2,
                               const float* __restrict__ watt, const float* __restrict__ ws,
                               float* __restrict__ ASRC, float* __restrict__ ADST,
                               float* __restrict__ VS, int n_nodes) {
    int wid = blockIdx.x * 4 + (threadIdx.x >> 6);
    if (wid >= n_nodes) return;
    int lane = threadIdx.x & 63;
    int b = blockIdx.y;
    float wa = watt[lane], wb = watt[FF + lane], wc = ws[lane];
    float x1 = P1[((size_t)b * n_nodes + wid) * FF + lane];
    float x2 = P2[((size_t)b * n_nodes + wid) * FF + lane];
    float s0 = x1 * wa, s1 = x1 * wb, s2 = x2 * wc;
    for (int m = 1; m < 64; m <<= 1) {
        s0 += __shfl_xor(s0, m);
        s1 += __shfl_xor(s1, m);
        s2 += __shfl_xor(s2, m);
    }
    if (lane == 0) {
        ASRC[b * n_nodes + wid] = s0;
        ADST[b * n_nodes + wid] = s1;
        VS[b * n_nodes + wid] = 1.f / (1.f + expf(-s2));
    }
}

// v[b,e] = exp(tanh(a_src[b,src[e]] + a_dst[b,dst[e]]))
__global__ void k_edge_v(const float* __restrict__ a_src, const float* __restrict__ a_dst,
                         const int* __restrict__ src, const int* __restrict__ dst,
                         float* __restrict__ v, int E, int n_nodes) {
    int e = blockIdx.x * 256 + threadIdx.x;
    if (e >= E) return;
    int b = blockIdx.y;
    v[(size_t)b * E + e] = expf(tanhf(a_src[b * n_nodes + src[e]] + a_dst[b * n_nodes + dst[e]]));
}

// fused: segment-sum of v, weighted gather-agg, + Xs*vs combine -> Out (pre-LN)
__global__ void k_agg_enc(const float* __restrict__ Xin, const float* __restrict__ v,
                          const float* __restrict__ Xs, const float* __restrict__ vs,
                          const int* __restrict__ dst, const int* __restrict__ rs,
                          const int* __restrict__ re, float* __restrict__ Out,
                          int n_nodes, int E) {
    long idx = (long)blockIdx.x * 256 + threadIdx.x;
    if (idx >= (long)n_nodes * FF) return;
    int r = (int)(idx >> 6), f = (int)(idx & 63);
    int b = blockIdx.y;
    int e0 = rs[r], e1 = re[r];
    float sv = 0.f, acc = 0.f;
    for (int e = e0; e < e1; e++) {
        float vv = v[(size_t)b * E + e];
        sv += vv;
        acc += vv * Xin[((size_t)b * n_nodes + dst[e]) * FF + f];
    }
    float o = (e1 > e0) ? acc / sv : 0.f;
    o += Xs[((size_t)b * n_nodes + r) * FF + f] * vs[b * n_nodes + r];
    Out[((size_t)b * n_nodes + r) * FF + f] = o;
}

// LN over node axis: accumulate sum & sumsq per (b,f)
__global__ void k_ln_stats(const float* __restrict__ X, float* __restrict__ sums,
                           int n_nodes, int Fdim, int npb) {
    int b = blockIdx.y;
    int f = threadIdx.x & (Fdim - 1);
    int nl = threadIdx.x / Fdim;
    int stride = 256 / Fdim;
    int n0 = blockIdx.x * npb;
    int n1 = n0 + npb; if (n1 > n_nodes) n1 = n_nodes;
    const float* xb = X + (size_t)b * n_nodes * Fdim;
    float s1 = 0.f, s2 = 0.f;
    for (int n = n0 + nl; n < n1; n += stride) {
        float x = xb[(size_t)n * Fdim + f];
        s1 += x; s2 += x * x;
    }
    __shared__ float sh1[256], sh2[256];
    sh1[threadIdx.x] = s1; sh2[threadIdx.x] = s2;
    __syncthreads();
    for (int o = 128; o >= Fdim; o >>= 1) {
        if (threadIdx.x < o) { sh1[threadIdx.x] += sh1[threadIdx.x + o]; sh2[threadIdx.x] += sh2[threadIdx.x + o]; }
        __syncthreads();
    }
    if (threadIdx.x < Fdim) {
        atomicAdd(&sums[(b * Fdim + threadIdx.x) * 2],     sh1[threadIdx.x]);
        atomicAdd(&sums[(b * Fdim + threadIdx.x) * 2 + 1], sh2[threadIdx.x]);
    }
}

// Y = relu((X - mu)*rsqrt(var+eps)*g[n] + bb[n])
__global__ void k_ln_apply_relu(const float* __restrict__ X, const float* __restrict__ sums,
                                const float* __restrict__ g, const float* __restrict__ bb,
                                float* __restrict__ Y, int n_nodes, int Fdim) {
    long idx = (long)blockIdx.x * 256 + threadIdx.x;
    if (idx >= (long)n_nodes * Fdim) return;
    int b = blockIdx.y;
    int n = (int)(idx / Fdim);
    int f = (int)(idx % Fdim);
    float s1 = sums[(b * Fdim + f) * 2], s2 = sums[(b * Fdim + f) * 2 + 1];
    float mu = s1 / n_nodes;
    float var = s2 / n_nodes - mu * mu;
    float rs = rsqrtf(var + EPSF);
    size_t o = (size_t)b * n_nodes * Fdim + idx;
    float y = (X[o] - mu) * rs * g[n] + bb[n];
    Y[o] = fmaxf(y, 0.f);
}

// deg[src[e]] += 1
__global__ void k_deg(const int* __restrict__ src, float* __restrict__ deg, int E) {
    int e = blockIdx.x * 256 + threadIdx.x;
    if (e < E) atomicAdd(&deg[src[e]], 1.0f);
}

// Out[b,n,f] = (n in [offset, offset+n_in)) ? Xs[b,n-offset,f] : 0
__global__ void k_init_region(float* __restrict__ Out, const float* __restrict__ Xs,
                              int n_rows, int offset, int n_in, int Fdim) {
    long idx = (long)blockIdx.x * 256 + threadIdx.x;
    if (idx >= (long)n_rows * Fdim) return;
    int b = blockIdx.y;
    int n = (int)(idx / Fdim), f = (int)(idx % Fdim);
    float v = 0.f;
    if (n >= offset && n < offset + n_in)
        v = Xs[((size_t)b * n_in + (n - offset)) * Fdim + f];
    Out[(size_t)b * n_rows * Fdim + idx] = v;
}

// Xg[b,src,f] += (1/deg[src]) * Xout[b,dst,f]   (atomic scatter)
__global__ void k_dec_agg(const float* __restrict__ Xout, const float* __restrict__ deg,
                          const int* __restrict__ src, const int* __restrict__ dst,
                          float* __restrict__ Xg, int E, int n_rows, int n_in, int Fdim) {
    long idx = (long)blockIdx.x * 256 + threadIdx.x;
    if (idx >= (long)E * Fdim) return;
    int e = (int)(idx / Fdim), f = (int)(idx % Fdim);
    int b = blockIdx.y;
    float coef = 1.0f / deg[src[e]];
    atomicAdd(&Xg[((size_t)b * n_rows + src[e]) * Fdim + f],
              coef * Xout[((size_t)b * n_in + dst[e]) * Fdim + f]);
}

// fused heads: wave per node. catt (5 outs, BN over b,d) + conc (1 out, BN over b)
__global__ void k_heads(const float* __restrict__ X, const float* __restrict__ Wa,
                        const float* __restrict__ wc, const float* __restrict__ ga,
                        const float* __restrict__ ba, const float* __restrict__ gc,
                        const float* __restrict__ bc, float* __restrict__ ATT,
                        float* __restrict__ INP, long xbs, int xoff) {
    int i = blockIdx.x * 4 + (threadIdx.x >> 6);
    if (i >= N_LAST) return;
    int lane = threadIdx.x & 63;
    float w0 = Wa[0 * FF + lane], w1 = Wa[1 * FF + lane], w2 = Wa[2 * FF + lane];
    float w3 = Wa[3 * FF + lane], w4 = Wa[4 * FF + lane];
    float wcv = wc[lane];
    float y[BB][D_ATT], yc[BB];
    float s1 = 0.f, s2 = 0.f;
#pragma unroll
    for (int b = 0; b < BB; b++) {
        float x = X[(size_t)b * xbs + (size_t)(i + xoff) * FF + lane];
        float p0 = x * w0, p1 = x * w1, p2 = x * w2, p3 = x * w3, p4 = x * w4, pc = x * wcv;
        for (int m = 1; m < 64; m <<= 1) {
            p0 += __shfl_xor(p0, m); p1 += __shfl_xor(p1, m); p2 += __shfl_xor(p2, m);
            p3 += __shfl_xor(p3, m); p4 += __shfl_xor(p4, m); pc += __shfl_xor(pc, m);
        }
        y[b][0] = p0; y[b][1] = p1; y[b][2] = p2; y[b][3] = p3; y[b][4] = p4;
        yc[b] = pc;
        s1 += p0 + p1 + p2 + p3 + p4;
        s2 += p0 * p0 + p1 * p1 + p2 * p2 + p3 * p3 + p4 * p4;
    }
    const float cnt = (float)(BB * D_ATT);
    float mu = s1 / cnt, var = s2 / cnt - mu * mu;
    float rsv = rsqrtf(var + EPSF);
    float gg = ga[i], bv = ba[i];
#pragma unroll
    for (int b = 0; b < BB; b++) {
        float yv = lane == 0 ? y[b][0] : lane == 1 ? y[b][1] : lane == 2 ? y[b][2]
                 : lane == 3 ? y[b][3] : y[b][4];
        if (lane < D_ATT)
            ATT[((size_t)b * N_LAST + i) * D_ATT + lane] = fmaxf((yv - mu) * rsv * gg + bv, 0.f);
    }
    float c1 = 0.f, c2 = 0.f;
#pragma unroll
    for (int b = 0; b < BB; b++) { c1 += yc[b]; c2 += yc[b] * yc[b]; }
    float muc = c1 / BB, varc = c2 / BB - muc * muc;
    float rc = rsqrtf(varc + EPSF);
    float ggc = gc[i], bvc = bc[i];
    if (lane < BB) {
        float v = lane == 0 ? yc[0] : lane == 1 ? yc[1] : lane == 2 ? yc[2] : lane == 3 ? yc[3]
                : lane == 4 ? yc[4] : lane == 5 ? yc[5] : lane == 6 ? yc[6] : yc[7];
        INP[(size_t)lane * N_LAST + i] = fmaxf((v - muc) * rc * ggc + bvc, 0.f);
    }
}

// scalar head: y[b] = X[b,i,:FIN]@w, BN over batch, relu -> Z (B, n_nodes)
template<int FIN>
__global__ void k_head_scalar(const float* __restrict__ X, const float* __restrict__ w,
                              const float* __restrict__ g, const float* __restrict__ bb,
                              float* __restrict__ Z, int n_nodes, long xbs, int xoff) {
    int i = blockIdx.x * 256 + threadIdx.x;
    if (i >= n_nodes) return;
    float y[BB];
    float s1 = 0.f, s2 = 0.f;
    const float4* wr = (const float4*)w;
    for (int b = 0; b < BB; b++) {
        const float4* xr = (const float4*)(X + (size_t)b * xbs + (size_t)(i + xoff) * FIN);
        float acc = 0.f;
#pragma unroll
        for (int q = 0; q < FIN / 4; q++) {
            float4 x = xr[q], u = wr[q];
            acc += x.x * u.x + x.y * u.y + x.z * u.z + x.w * u.w;
        }
        y[b] = acc; s1 += acc; s2 += acc * acc;
    }
    float mu = s1 / BB, var = s2 / BB - mu * mu;
    float rs = rsqrtf(var + EPSF);
    float gg = g[i], bv = bb[i];
    for (int b = 0; b < BB; b++)
        Z[(size_t)b * n_nodes + i] = fmaxf((y[b] - mu) * rs * gg + bv, 0.f);
}

// xD[b, col[e]] += outD[b, row[e]] * tD[e]
__global__ void k_xd(const float* __restrict__ outD, const float* __restrict__ tD,
                     const int* __restrict__ row, const int* __restrict__ col,
                     float* __restrict__ xD, int nnz) {
    int e = blockIdx.x * 256 + threadIdx.x;
    if (e >= nnz) return;
    int b = blockIdx.y;
    atomicAdd(&xD[(size_t)b * N_GENES + col[e]], outD[(size_t)b * N_GO + row[e]] * tD[e]);
}

// latent layer 1 fused
__global__ void k_lat1(const float* __restrict__ INP, const float* __restrict__ W,
                       const float* __restrict__ g, const float* __restrict__ bb,
                       float* __restrict__ H1R) {
    int j = blockIdx.x;
    int w = threadIdx.x >> 6;
    int lane = threadIdx.x & 63;
    const float* xr = INP + (size_t)w * N_LAST;
    const float* wr = W + (size_t)j * N_LAST;
    float s = 0.f;
    for (int k = lane; k < N_LAST; k += 64) s += xr[k] * wr[k];
    for (int o = 32; o > 0; o >>= 1) s += __shfl_down(s, o);
    __shared__ float sh[BB];
    if (lane == 0) sh[w] = s;
    __syncthreads();
    if (threadIdx.x < BB) {
        float s1 = 0.f, s2 = 0.f;
        for (int q = 0; q < BB; q++) { float y = sh[q]; s1 += y; s2 += y * y; }
        float mu = s1 / BB, var = s2 / BB - mu * mu;
        float rs = rsqrtf(var + EPSF);
        H1R[threadIdx.x * 32 + j] = fmaxf((sh[threadIdx.x] - mu) * rs * g[j] + bb[j], 0.f);
    }
}

// latent layer 2 fused
__global__ void k_lat2(const float* __restrict__ H1R, const float* __restrict__ W2,
                       const float* __restrict__ g, const float* __restrict__ bb,
                       float* __restrict__ out_lat) {
    int b = threadIdx.x >> 4, j = threadIdx.x & 15;
    float acc = 0.f;
    for (int k = 0; k < 32; k++) acc += H1R[b * 32 + k] * W2[j * 32 + k];
    __shared__ float sh[128];
    sh[threadIdx.x] = acc;
    __syncthreads();
    float s1 = 0.f, s2 = 0.f;
    for (int q = 0; q < BB; q++) { float y = sh[q * 16 + j]; s1 += y; s2 += y * y; }
    float mu = s1 / BB, var = s2 / BB - mu * mu;
    float rs = rsqrtf(var + EPSF);
    out_lat[b * 16 + j] = fmaxf((acc - mu) * rs * g[j] + bb[j], 0.f);
}

// ============================================================
extern "C" void kernel_launch(void* const* d_in, const int* in_sizes, int n_in,
                              void* d_out, int out_size, void* d_ws, size_t ws_size,
                              hipStream_t stream) {
    const float* data      = (const float*)d_in[0];
    const float* t         = (const float*)d_in[1];
    const float* t_D       = (const float*)d_in[2];
    const float* w_inc0    = (const float*)d_in[3];
    const float* w_inc1    = (const float*)d_in[4];
    const float* w_s0      = (const float*)d_in[5];
    const float* w_s1      = (const float*)d_in[6];
    const float* w_att_in0 = (const float*)d_in[7];
    const float* w_att_in1 = (const float*)d_in[8];
    const float* w_att_s0  = (const float*)d_in[9];
    const float* w_att_s1  = (const float*)d_in[10];
    const float* gb_g0     = (const float*)d_in[11];
    const float* gb_b0     = (const float*)d_in[12];
    const float* gb_g1     = (const float*)d_in[13];
    const float* gb_b1     = (const float*)d_in[14];
    const float* w_out0    = (const float*)d_in[15];
    const float* w_out1    = (const float*)d_in[16];
    const float* w_sout0   = (const float*)d_in[17];
    const float* w_sout1   = (const float*)d_in[18];
    const float* gbd_g0    = (const float*)d_in[19];
    const float* gbd_b0    = (const float*)d_in[20];
    const float* gbd_g1    = (const float*)d_in[21];
    const float* gbd_b1    = (const float*)d_in[22];
    const float* catt_w    = (const float*)d_in[23];
    const float* catt_bn_g = (const float*)d_in[24];
    const float* catt_bn_b = (const float*)d_in[25];
    const float* conc_w    = (const float*)d_in[26];
    const float* b_bn_g    = (const float*)d_in[27];
    const float* b_bn_b    = (const float*)d_in[28];
    const float* concd_w   = (const float*)d_in[29];
    const float* bd_bn_g   = (const float*)d_in[30];
    const float* bd_bn_b   = (const float*)d_in[31];
    const float* lat_w1    = (const float*)d_in[32];
    const float* lat_bn1_g = (const float*)d_in[33];
    const float* lat_bn1_b = (const float*)d_in[34];
    const float* lat_w2    = (const float*)d_in[35];
    const float* lat_bn2_g = (const float*)d_in[36];
    const float* lat_bn2_b = (const float*)d_in[37];
    const int* Ag_row   = (const int*)d_in[38];
    const int* Ag_col   = (const int*)d_in[39];
    const int* enc_src0 = (const int*)d_in[40];
    const int* enc_dst0 = (const int*)d_in[41];
    const int* enc_src1 = (const int*)d_in[42];
    const int* enc_dst1 = (const int*)d_in[43];
    const int* dec_src0 = (const int*)d_in[44];
    const int* dec_dst0 = (const int*)d_in[45];
    const int* dec_src1 = (const int*)d_in[46];
    const int* dec_dst1 = (const int*)d_in[47];

    const int nnz = in_sizes[2];
    const int E0  = in_sizes[40];
    const int E1  = in_sizes[42];
    const int ED0 = in_sizes[44];
    const int ED1 = in_sizes[46];

    // ---- workspace arena ----
    char* wsb = (char*)d_ws;
    size_t off = 0;
    auto alloc = [&](size_t bytes) -> void* {
        void* p = wsb + off;
        off += (bytes + 255) & ~(size_t)255;
        return p;
    };
    const size_t ARENA = (size_t)BB * N_GO * FF;
    float* P0 = (float*)alloc(ARENA * 4);
    float* P1 = (float*)alloc(ARENA * 4);
    float* P2 = (float*)alloc(ARENA * 4);
    float* P3 = (float*)alloc(ARENA * 4);
    float* EDGEV = (float*)alloc((size_t)BB * E0 * 4);
    float* ASRC = (float*)alloc((size_t)BB * N_GO * 4);
    float* ADST = (float*)alloc((size_t)BB * N_GO * 4);
    float* DEG  = (float*)alloc((size_t)N_GO * 4);
    float* VS   = (float*)alloc((size_t)BB * N_GO * 4);
    float* SUMS = (float*)alloc(2 * BB * FF * 4);
    float* INP  = (float*)alloc((size_t)BB * N_LAST * 4);
    float* OUTD = (float*)alloc((size_t)BB * N_GO * 4);
    float* H1R  = (float*)alloc(BB * 32 * 4);
    int* RS = (int*)alloc(N_GO * 4);
    int* RE = (int*)alloc(N_GO * 4);

    float* out_lat = (float*)d_out;                 // (B,16)
    float* out_xd  = out_lat + BB * L_DIM;          // (B,20000)
    float* out_att = out_xd + (size_t)BB * N_GENES; // (B,4000,5)

    dim3 blk(256);
    auto g1 = [](long n) { return dim3((unsigned)((n + 255) / 256)); };
    auto g2 = [](long n, int y) { return dim3((unsigned)((n + 255) / 256), (unsigned)y); };
    const int LNB = 512;                 // blocks for reg-linear
    const int LWAVES = LNB * 4;

    // ---- stage 0: gene -> GO ----
    hipMemsetAsync(RS, 0, N_GO * 4, stream);
    hipMemsetAsync(RE, 0, N_GO * 4, stream);
    k_row_bounds<<<g1(nnz), blk, 0, stream>>>(Ag_row, RS, RE, nnz);
    k_gene2go_w<<<dim3((N_GO + 3) / 4), blk, 0, stream>>>(data, t, Ag_col, RS, RE, P0, nnz);

    // ---- encoder 0 (n=12000) ----
    k_linear2_reg<IN_F, FF><<<dim3(LNB), blk, 0, stream>>>(P0, w_inc0, w_s0, P1, P2, N_GO, (long)N_GO * IN_F, 0, LWAVES);
    k_node_scalars<<<g2((long)N_GO * 64, BB), blk, 0, stream>>>(P1, P2, w_att_in0, w_att_s0, ASRC, ADST, VS, N_GO);
    hipMemsetAsync(RS, 0, N_GO * 4, stream);
    hipMemsetAsync(RE, 0, N_GO * 4, stream);
    k_row_bounds<<<g1(E0), blk, 0, stream>>>(enc_src0, RS, RE, E0);
    k_edge_v<<<g2(E0, BB), blk, 0, stream>>>(ASRC, ADST, enc_src0, enc_dst0, EDGEV, E0, N_GO);
    k_agg_enc<<<g2((long)N_GO * FF, BB), blk, 0, stream>>>(P1, EDGEV, P2, VS, enc_dst0, RS, RE, P3, N_GO, E0);
    hipMemsetAsync(SUMS, 0, 2 * BB * FF * 4, stream);
    k_ln_stats<<<dim3((N_GO + 511) / 512, BB), blk, 0, stream>>>(P3, SUMS, N_GO, FF, 512);
    k_ln_apply_relu<<<g2((long)N_GO * FF, BB), blk, 0, stream>>>(P3, SUMS, gb_g0, gb_b0, P0, N_GO, FF);

    // ---- encoder 1 (n=8000, x = P0[:,4000:,:]) ----
    const int N1 = N_GO - P0_; // 8000
    k_linear2_reg<FF, FF><<<dim3(LNB), blk, 0, stream>>>(P0, w_inc1, w_s1, P1, P2, N1, (long)N_GO * FF, P0_, LWAVES);
    k_node_scalars<<<g2((long)N1 * 64, BB), blk, 0, stream>>>(P1, P2, w_att_in1, w_att_s1, ASRC, ADST, VS, N1);
    hipMemsetAsync(RS, 0, N_GO * 4, stream);
    hipMemsetAsync(RE, 0, N_GO * 4, stream);
    k_row_bounds<<<g1(E1), blk, 0, stream>>>(enc_src1, RS, RE, E1);
    k_edge_v<<<g2(E1, BB), blk, 0, stream>>>(ASRC, ADST, enc_src1, enc_dst1, EDGEV, E1, N1);
    k_agg_enc<<<g2((long)N1 * FF, BB), blk, 0, stream>>>(P1, EDGEV, P2, VS, enc_dst1, RS, RE, P3, N1, E1);
    hipMemsetAsync(SUMS, 0, 2 * BB * FF * 4, stream);
    k_ln_stats<<<dim3((N1 + 511) / 512, BB), blk, 0, stream>>>(P3, SUMS, N1, FF, 512);
    k_ln_apply_relu<<<g2((long)N1 * FF, BB), blk, 0, stream>>>(P3, SUMS, gb_g1, gb_b1, P0, N1, FF);

    // ---- heads (x = P0[:,4000:,:] of (B,8000,64)) ----
    k_heads<<<dim3((N_LAST + 3) / 4), blk, 0, stream>>>(P0, catt_w, conc_w, catt_bn_g, catt_bn_b,
                                                        b_bn_g, b_bn_b, out_att, INP, (long)N1 * FF, P0_);

    // ---- decoder 0 (in n=4000 -> rows 8000) ----
    k_linear2_reg<FF, FF><<<dim3(LNB), blk, 0, stream>>>(P0, w_out0, w_sout0, P1, P2, N_LAST, (long)N1 * FF, P0_, LWAVES);
    hipMemsetAsync(DEG, 0, 8000 * 4, stream);
    k_deg<<<g1(ED0), blk, 0, stream>>>(dec_src0, DEG, ED0);
    k_init_region<<<g2((long)8000 * FF, BB), blk, 0, stream>>>(P3, P2, 8000, 4000, N_LAST, FF);
    k_dec_agg<<<g2((long)ED0 * FF, BB), blk, 0, stream>>>(P1, DEG, dec_src0, dec_dst0, P3, ED0, 8000, N_LAST, FF);
    hipMemsetAsync(SUMS, 0, 2 * BB * FF * 4, stream);
    k_ln_stats<<<dim3((8000 + 511) / 512, BB), blk, 0, stream>>>(P3, SUMS, 8000, FF, 512);
    k_ln_apply_relu<<<g2((long)8000 * FF, BB), blk, 0, stream>>>(P3, SUMS, gbd_g0, gbd_b0, P0, 8000, FF);

    // ---- decoder 1 (in n=8000 F=64 -> rows 12000 F=8) ----
    k_linear2_reg<FF, IN_F><<<dim3(LNB), blk, 0, stream>>>(P0, w_out1, w_sout1, P1, P2, 8000, (long)8000 * FF, 0, LWAVES);
    hipMemsetAsync(DEG, 0, N_GO * 4, stream);
    k_deg<<<g1(ED1), blk, 0, stream>>>(dec_src1, DEG, ED1);
    k_init_region<<<g2((long)N_GO * IN_F, BB), blk, 0, stream>>>(P3, P2, N_GO, 4000, 8000, IN_F);
    k_dec_agg<<<g2((long)ED1 * IN_F, BB), blk, 0, stream>>>(P1, DEG, dec_src1, dec_dst1, P3, ED1, N_GO, 8000, IN_F);
    hipMemsetAsync(SUMS, 0, 2 * BB * IN_F * 4, stream);
    k_ln_stats<<<dim3((N_GO + 511) / 512, BB), blk, 0, stream>>>(P3, SUMS, N_GO, IN_F, 512);
    k_ln_apply_relu<<<g2((long)N_GO * IN_F, BB), blk, 0, stream>>>(P3, SUMS, gbd_g1, gbd_b1, P0, N_GO, IN_F);

    // ---- out_D head + x_D scatter ----
    k_head_scalar<IN_F><<<g1(N_GO), blk, 0, stream>>>(P0, concd_w, bd_bn_g, bd_bn_b, OUTD, N_GO, (long)N_GO * IN_F, 0);
    hipMemsetAsync(out_xd, 0, (size_t)BB * N_GENES * 4, stream);
    k_xd<<<g2(nnz, BB), blk, 0, stream>>>(OUTD, t_D, Ag_row, Ag_col, out_xd, nnz);

    // ---- latent MLP (fused) ----
    k_lat1<<<dim3(32), dim3(512), 0, stream>>>(INP, lat_w1, lat_bn1_g, lat_bn1_b, H1R);
    k_lat2<<<dim3(1), dim3(128), 0, stream>>>(H1R, lat_w2, lat_bn2_g, lat_bn2_b, out_lat);

    (void)n_in; (void)out_size; (void)ws_size;
}